// Round 11
// baseline (643.087 us; speedup 1.0000x reference)
//
#include <hip/hip_runtime.h>
#include <math.h>

#define NNODES 50000
#define NEDGES 262144
#define NEG_SLOPE 0.2f
#define NBINS (2 * NNODES)
#define NXP 391                    // ceil(50000/128)
#define NWG_GEMM (2 * NXP * 6)     // 4692

// fused_prep block ranges
#define CONV_B 25000               // 2*HN/4/256
#define HIST_B 2048                // 2*NEDGES/256
#define PREP_B 1538                // 2 + 2*768

typedef __attribute__((ext_vector_type(8))) short short8;   // 8 x bf16 (16B)
typedef __attribute__((ext_vector_type(4))) float f32x4;    // MFMA acc
typedef __attribute__((ext_vector_type(2))) float f32x2;
typedef __attribute__((ext_vector_type(4))) unsigned short u16x4;

// aux layout (floats): [0,2N) ps per rel (rel*N+src) ; [2N,4N) pd per rel ;
//                      [4N,6N) hl per type (t*N+node) ; [6N,8N) hr per type
#define AUX_PS 0
#define AUX_PD (2 * NNODES)
#define AUX_HL (4 * NNODES)
#define AUX_HR (6 * NNODES)

// ---------- helpers ----------
__device__ __forceinline__ float elu_f(float x) { return x > 0.f ? x : (__expf(x) - 1.f); }
__device__ __forceinline__ float bf2f(unsigned short u) {
    return __uint_as_float(((unsigned)u) << 16);
}
__device__ __forceinline__ f32x2 bfp2f(unsigned p) {   // 2 packed bf16 -> 2 f32
    f32x2 r;
    r.x = __uint_as_float(p << 16);
    r.y = __uint_as_float(p & 0xffff0000u);
    return r;
}
__device__ __forceinline__ unsigned short f2bf(float f) {
    unsigned u = __float_as_uint(f);
    unsigned r = (u + 0x7fffu + ((u >> 16) & 1u)) >> 16;   // RNE
    return (unsigned short)r;
}

// ---------- fused: f32->bf16 conv (hA,hB) + edge histogram + weight pack + uv precompute
__global__ __launch_bounds__(256) void fused_prep(
    const float* __restrict__ hA, const float* __restrict__ hB,
    unsigned short* __restrict__ hAb, unsigned short* __restrict__ hBb, int half,
    const int* __restrict__ dab, const int* __restrict__ dba, int* __restrict__ counts,
    const float* __restrict__ Wself, const float* __restrict__ Wsrc, const float* __restrict__ Wdst,
    const float* __restrict__ bself, const float* __restrict__ bsrc, const float* __restrict__ bdst,
    const float* __restrict__ Wq, const float* __restrict__ bq,
    const float* __restrict__ Wk, const float* __restrict__ bk,
    const float* __restrict__ Wal, const float* __restrict__ bal,
    const float* __restrict__ War, const float* __restrict__ bar,
    unsigned short* __restrict__ Wt, float* __restrict__ biasF,
    float* __restrict__ u_l, float* __restrict__ u_r,
    float* __restrict__ c_l, float* __restrict__ c_r)
{
    int b = blockIdx.x;
    if (b < CONV_B) {
        int i = (b * 256 + threadIdx.x) * 4;
        if (i >= 2 * half) return;
        const float* in = (i < half) ? hA : hB;
        unsigned short* out = (i < half) ? hAb : hBb;
        int k = (i < half) ? i : i - half;
        float4 v = *reinterpret_cast<const float4*>(&in[k]);
        u16x4 o;
        o[0] = f2bf(v.x); o[1] = f2bf(v.y); o[2] = f2bf(v.z); o[3] = f2bf(v.w);
        *reinterpret_cast<u16x4*>(&out[k]) = o;
        return;
    }
    if (b < CONV_B + HIST_B) {
        int e = (b - CONV_B) * 256 + threadIdx.x;
        if (e < NEDGES) atomicAdd(&counts[dab[e]], 1);
        else atomicAdd(&counts[NNODES + dba[e - NEDGES]], 1);
        return;
    }
    int pb = b - CONV_B - HIST_B;
    if (pb < 2) {
        int t = pb;
        int d = threadIdx.x;
        float sl = 0.f, sr = 0.f;
        for (int j = 0; j < 64; ++j) {
            sl += Wk[((size_t)t * 256 + d) * 64 + j] * Wal[t * 64 + j];
            sr += Wq[((size_t)t * 256 + d) * 64 + j] * War[t * 64 + j];
        }
        u_l[t * 256 + d] = sl;
        u_r[t * 256 + d] = sr;
        if (d == 0) {
            float cl = bal[t], cr = bar[t];
            for (int j = 0; j < 64; ++j) {
                cl += bk[t * 64 + j] * Wal[t * 64 + j];
                cr += bq[t * 64 + j] * War[t * 64 + j];
            }
            c_l[t] = cl; c_r[t] = cr;
        }
        return;
    }
    int r = pb - 2;                // 0..1535 = t*768 + n
    int t = r / 768;
    int n = r % 768;
    int seg = n >> 8;
    int nn = n & 255;
    const float* W; const float* bv; int ti;
    if (seg == 0)      { W = Wself; bv = bself; ti = t; }
    else if (seg == 1) { W = Wsrc;  bv = bsrc;  ti = t; }
    else               { W = Wdst;  bv = bdst;  ti = 1 - t; }
    int k = threadIdx.x;
    float val = W[(size_t)ti * 65536 + (size_t)k * 256 + nn];
    Wt[(size_t)r * 256 + k] = f2bf(val);
    if (k == 0) biasF[r] = bv[ti * 256 + nn];
}

// ---------- scan step 1 (vectorized, 1024 bins/block) + degree histogram ----------
__global__ __launch_bounds__(256) void scan1v(const int* __restrict__ counts,
                                              int* __restrict__ incl,
                                              int* __restrict__ bsum,
                                              int* __restrict__ deghist, int n) {
    __shared__ int s[256];
    __shared__ int dh[64];
    int t = threadIdx.x;
    if (t < 64) dh[t] = 0;
    int base = blockIdx.x * 1024 + t * 4;
    int4 v = make_int4(0, 0, 0, 0);
    if (base < n) v = *reinterpret_cast<const int4*>(&counts[base]);
    int l0 = v.x, l1 = l0 + v.y, l2 = l1 + v.z, l3 = l2 + v.w;
    s[t] = l3;
    __syncthreads();
    if (base < n) {    // degree histogram (LDS-local, merged to global below)
        atomicAdd(&dh[min(v.x, 63)], 1);
        atomicAdd(&dh[min(v.y, 63)], 1);
        atomicAdd(&dh[min(v.z, 63)], 1);
        atomicAdd(&dh[min(v.w, 63)], 1);
    }
#pragma unroll
    for (int off = 1; off < 256; off <<= 1) {
        int x = (t >= off) ? s[t - off] : 0;
        __syncthreads();
        s[t] += x;
        __syncthreads();
    }
    int ex = s[t] - l3;
    if (base < n)
        *reinterpret_cast<int4*>(&incl[base]) = make_int4(ex + l0, ex + l1, ex + l2, ex + l3);
    if (t == 255) bsum[blockIdx.x] = s[255];
    __syncthreads();
    if (t < 64 && dh[t]) atomicAdd(&deghist[t], dh[t]);
}

// ---------- scan steps 2+3 merged: each block locally scans bsum (nb<=128);
// writes row_start (exclusive + sentinel), cursor; block 0 computes descending deg offsets.
__global__ __launch_bounds__(256) void scan23v(const int* __restrict__ counts,
                                               int* __restrict__ incl_to_rs,
                                               const int* __restrict__ bsum,
                                               int* __restrict__ cursor,
                                               const int* __restrict__ deghist,
                                               int* __restrict__ degcur,
                                               int n, int nb) {
    __shared__ int s[128];
    int t = threadIdx.x;
    if (t < 128) s[t] = (t < nb) ? bsum[t] : 0;
    __syncthreads();
#pragma unroll
    for (int off = 1; off < 128; off <<= 1) {
        int x = 0;
        if (t < 128 && t >= off) x = s[t - off];
        __syncthreads();
        if (t < 128) s[t] += x;
        __syncthreads();
    }
    if (blockIdx.x == 0 && t == 0) {
        incl_to_rs[n] = s[nb - 1];               // sentinel = total edges
        int off = 0;                              // descending-degree exclusive offsets
        for (int b2 = 63; b2 >= 0; --b2) { degcur[b2] = off; off += deghist[b2]; }
    }
    int base = blockIdx.x * 1024 + t * 4;
    if (base >= n) return;
    int bofs = (blockIdx.x > 0) ? s[blockIdx.x - 1] : 0;
    int4 ic = *reinterpret_cast<const int4*>(&incl_to_rs[base]);
    int4 cn = *reinterpret_cast<const int4*>(&counts[base]);
    int4 st = make_int4(bofs + ic.x - cn.x, bofs + ic.y - cn.y,
                        bofs + ic.z - cn.z, bofs + ic.w - cn.w);
    *reinterpret_cast<int4*>(&incl_to_rs[base]) = st;
    *reinterpret_cast<int4*>(&cursor[base]) = st;
}

// ---------- edge scatter + degree-sorted node scatter (merged) ----------
__global__ __launch_bounds__(256) void scatter2n(const int* __restrict__ sab,
                                                 const int* __restrict__ dab,
                                                 const int* __restrict__ sba,
                                                 const int* __restrict__ dba,
                                                 int* __restrict__ cursor,
                                                 int* __restrict__ sorted_src,
                                                 const int* __restrict__ row_start,
                                                 int* __restrict__ degcur,
                                                 int* __restrict__ node_order) {
    int b = blockIdx.x;
    if (b < HIST_B) {
        int e = b * 256 + threadIdx.x;
        if (e < NEDGES) {
            int pos = atomicAdd(&cursor[dab[e]], 1);
            sorted_src[pos] = sab[e];
        } else {
            int k = e - NEDGES;
            int pos = atomicAdd(&cursor[NNODES + dba[k]], 1);
            sorted_src[pos] = sba[k];
        }
        return;
    }
    int idx = (b - HIST_B) * 256 + threadIdx.x;
    if (idx >= NBINS) return;
    int cnt = row_start[idx + 1] - row_start[idx];
    int pos = atomicAdd(&degcur[min(cnt, 63)], 1);
    node_order[pos] = idx;
}

// ---------- fused bf16 MFMA GEMM (R7 structure, known-good ~90us) ----------
__global__ __launch_bounds__(256, 4) void gemm_mfma(
    const unsigned short* __restrict__ hAb,
    const unsigned short* __restrict__ hBb,
    const unsigned short* __restrict__ Wt,
    const float* __restrict__ biasF,
    const float* __restrict__ attn_v,
    const float* __restrict__ u_l,
    const float* __restrict__ u_r,
    unsigned short* __restrict__ bufA,
    unsigned short* __restrict__ bufB,
    float* __restrict__ aux,
    int M)
{
    __shared__ unsigned short lds[16384];   // 32 KB: 4x8KB stage bufs; reused as C tile
    const int tid = threadIdx.x;
    const int lane = tid & 63;
    const int w = tid >> 6;
    const int wm = w >> 1, wn = w & 1;

    // bijective XCD swizzle (m204)
    const int nwg = NWG_GEMM;
    const int q = nwg / 8, r = nwg % 8;
    int orig = blockIdx.x;
    int xcd = orig % 8, idx = orig / 8;
    int wgid = (xcd < r) ? (xcd * (q + 1) + idx) : (r * (q + 1) + (xcd - r) * q + idx);
    int t   = wgid / (NXP * 6);
    int rem = wgid % (NXP * 6);
    int xp  = rem / 6;
    int yc  = rem % 6;

    const int row0 = xp * 128;
    const int col0 = yc * 128;
    const unsigned short* Ain = t ? hBb : hAb;
    const unsigned short* Wtt = Wt + (size_t)t * 768 * 256;
    const float* bias = biasF + t * 768;
    unsigned short* Cout = t ? bufB : bufA;

    f32x4 acc[4][4] = {};

    const unsigned short* gA[2];
    const unsigned short* gB[2];
#pragma unroll
    for (int rr = 0; rr < 2; ++rr) {
        int qq = rr * 256 + tid;
        int row = qq >> 2;
        int c = (qq & 3) ^ ((row >> 1) & 3);
        int ga = min(row0 + row, M - 1);
        gA[rr] = Ain + (size_t)ga * 256 + c * 8;
        gB[rr] = Wtt + (size_t)(col0 + row) * 256 + c * 8;
    }

#define STAGE(buf, kt)                                                                   \
    {                                                                                    \
        unsigned short* Ad = lds + (buf) * 4096;                                         \
        unsigned short* Bd = lds + 8192 + (buf) * 4096;                                  \
        _Pragma("unroll")                                                                \
        for (int rr = 0; rr < 2; ++rr) {                                                 \
            __builtin_amdgcn_global_load_lds(                                            \
                (const __attribute__((address_space(1))) unsigned int*)(gA[rr] + (kt)),  \
                (__attribute__((address_space(3))) unsigned int*)(Ad + ((rr * 256 + w * 64) << 3)), \
                16, 0, 0);                                                               \
            __builtin_amdgcn_global_load_lds(                                            \
                (const __attribute__((address_space(1))) unsigned int*)(gB[rr] + (kt)),  \
                (__attribute__((address_space(3))) unsigned int*)(Bd + ((rr * 256 + w * 64) << 3)), \
                16, 0, 0);                                                               \
        }                                                                                \
    }

    STAGE(0, 0);        // tile 0 (4 loads/thread)
    STAGE(1, 32);       // tile 1 (8 outstanding)

#pragma unroll
    for (int it = 0; it < 8; ++it) {
        const int cur = it & 1;
        if (it < 7) { asm volatile("s_waitcnt vmcnt(4)" ::: "memory"); }
        else        { asm volatile("s_waitcnt vmcnt(0)" ::: "memory"); }
        __builtin_amdgcn_s_barrier();
        __builtin_amdgcn_sched_barrier(0);

        const unsigned short* As = lds + cur * 4096;
        const unsigned short* Bs = lds + 8192 + cur * 4096;
        short8 a[4], b[4];
#pragma unroll
        for (int i = 0; i < 4; ++i) {
            int ar = wm * 64 + i * 16 + (lane & 15);
            a[i] = *reinterpret_cast<const short8*>(
                &As[ar * 32 + (((lane >> 4) ^ ((ar >> 1) & 3)) << 3)]);
            int br = wn * 64 + i * 16 + (lane & 15);
            b[i] = *reinterpret_cast<const short8*>(
                &Bs[br * 32 + (((lane >> 4) ^ ((br >> 1) & 3)) << 3)]);
        }
#pragma unroll
        for (int i = 0; i < 4; ++i)
#pragma unroll
            for (int j = 0; j < 4; ++j)
                acc[i][j] = __builtin_amdgcn_mfma_f32_16x16x32_bf16(a[i], b[j], acc[i][j], 0, 0, 0);

        asm volatile("s_waitcnt lgkmcnt(0)" ::: "memory");
        __builtin_amdgcn_sched_barrier(0);
        __builtin_amdgcn_s_barrier();
        if (it < 6) STAGE(cur, (it + 2) * 32);
    }
#undef STAGE

    // ---- epilogue: acc (+bias) -> LDS [128][128] bf16 with per-row col-group XOR
#pragma unroll
    for (int j = 0; j < 4; ++j) {
        int colg = wn * 4 + j;
        int ci = lane & 15;
        float bv = bias[col0 + colg * 16 + ci];
#pragma unroll
        for (int i = 0; i < 4; ++i) {
            int rowb = wm * 64 + i * 16 + ((lane >> 4) << 2);
#pragma unroll
            for (int v = 0; v < 4; ++v) {
                int row = rowb + v;
                int g2 = colg ^ ((row >> 2) & 3);
                lds[row * 128 + g2 * 16 + ci] = f2bf(acc[i][j][v] + bv);
            }
        }
    }
    __syncthreads();

    const int seg = yc >> 1;                   // 0:z, 1:ftS, 2:ftD
    const float* avp1; float* axp1;
    const float* avp2 = nullptr; float* axp2 = nullptr;
    if (seg == 0) {
        avp1 = u_l + t * 256;            axp1 = aux + AUX_HL + (size_t)t * NNODES;
        avp2 = u_r + t * 256;            axp2 = aux + AUX_HR + (size_t)t * NNODES;
    } else if (seg == 1) {
        avp1 = attn_v + t * 256;         axp1 = aux + AUX_PS + (size_t)t * NNODES;
    } else {
        avp1 = attn_v + (1 - t) * 256;   axp1 = aux + AUX_PD + (size_t)(1 - t) * NNODES;
    }

#pragma unroll
    for (int p = 0; p < 8; ++p) {
        int idx = p * 256 + tid;
        int row = idx >> 4;
        int ch = idx & 15;
        int g2 = (ch >> 1) ^ ((row >> 2) & 3);
        int grow = row0 + row;
        bool ok = grow < M;
        short8 val = *reinterpret_cast<const short8*>(&lds[row * 128 + g2 * 16 + ((ch & 1) << 3)]);
        if (ok)
            *reinterpret_cast<short8*>(&Cout[(size_t)grow * 768 + col0 + ch * 8]) = val;
        int colb = (yc & 1) * 128 + ch * 8;
        float4 w0v = *reinterpret_cast<const float4*>(&avp1[colb]);
        float4 w1v = *reinterpret_cast<const float4*>(&avp1[colb + 4]);
        float p1 = w0v.x * bf2f((unsigned short)val[0]) + w0v.y * bf2f((unsigned short)val[1])
                 + w0v.z * bf2f((unsigned short)val[2]) + w0v.w * bf2f((unsigned short)val[3])
                 + w1v.x * bf2f((unsigned short)val[4]) + w1v.y * bf2f((unsigned short)val[5])
                 + w1v.z * bf2f((unsigned short)val[6]) + w1v.w * bf2f((unsigned short)val[7]);
        p1 += __shfl_xor(p1, 1);
        p1 += __shfl_xor(p1, 2);
        p1 += __shfl_xor(p1, 4);
        p1 += __shfl_xor(p1, 8);
        if ((tid & 15) == 0 && ok) atomicAdd(&axp1[grow], p1);
        if (avp2) {
            float4 y0 = *reinterpret_cast<const float4*>(&avp2[colb]);
            float4 y1 = *reinterpret_cast<const float4*>(&avp2[colb + 4]);
            float p2 = y0.x * bf2f((unsigned short)val[0]) + y0.y * bf2f((unsigned short)val[1])
                     + y0.z * bf2f((unsigned short)val[2]) + y0.w * bf2f((unsigned short)val[3])
                     + y1.x * bf2f((unsigned short)val[4]) + y1.y * bf2f((unsigned short)val[5])
                     + y1.z * bf2f((unsigned short)val[6]) + y1.w * bf2f((unsigned short)val[7]);
            p2 += __shfl_xor(p2, 1);
            p2 += __shfl_xor(p2, 2);
            p2 += __shfl_xor(p2, 4);
            p2 += __shfl_xor(p2, 8);
            if ((tid & 15) == 0 && ok) atomicAdd(&axp2[grow], p2);
        }
    }
}

// ---------- fully fused per-dst GATv2 + node attention + combine
// 16 lanes/dst, 4 dsts/wave, DEGREE-SORTED node order (equal cnt within a wave
// -> no divergence waste). lrelu factorization; batch-4 loads / process-2.
__global__ __launch_bounds__(256) void gat_fused(
    const unsigned short* __restrict__ bufA, const unsigned short* __restrict__ bufB,
    const int* __restrict__ sorted_src, const int* __restrict__ row_start,
    const int* __restrict__ node_order,
    const float* __restrict__ attn_v, const float* __restrict__ gbias,
    const float* __restrict__ u_l,
    const float* __restrict__ c_l, const float* __restrict__ c_r,
    const float* __restrict__ aux,
    float* __restrict__ out)
{
    const int tid = threadIdx.x;
    const int l = tid & 15;            // lane in 16-group
    const int gBase = tid & 48;        // group base lane within wave
    const int nd0 = blockIdx.x * 16 + (tid >> 4);
    if (nd0 >= 2 * NNODES) return;
    const int nd = node_order[nd0];    // degree-sorted
    const int rel = nd >= NNODES;      // 0: ab (dst type B), 1: ba (dst type A)
    const int d = nd - rel * NNODES;
    const int td = rel ? 0 : 1;        // dst node type

    const unsigned short* zbuf = td ? bufB : bufA;
    const unsigned short* ftS = (rel ? bufB : bufA) + 256;
    const unsigned short* ftD = zbuf + 512;
    const float clv = c_l[td], crv = c_r[td];

    // per-lane dims [l*16, l*16+16) as f32x2 pairs
    f32x2 fd2[8], av2[8];
    {
        const unsigned short* fdp = &ftD[(size_t)d * 768 + l * 16];
        uint4 d0 = *reinterpret_cast<const uint4*>(fdp);
        uint4 d1 = *reinterpret_cast<const uint4*>(fdp + 8);
        fd2[0] = bfp2f(d0.x); fd2[1] = bfp2f(d0.y); fd2[2] = bfp2f(d0.z); fd2[3] = bfp2f(d0.w);
        fd2[4] = bfp2f(d1.x); fd2[5] = bfp2f(d1.y); fd2[6] = bfp2f(d1.z); fd2[7] = bfp2f(d1.w);
        const float* avp = attn_v + rel * 256 + l * 16;
#pragma unroll
        for (int e = 0; e < 4; ++e) {
            float4 a = *reinterpret_cast<const float4*>(&avp[e * 4]);
            av2[2 * e].x = a.x; av2[2 * e].y = a.y;
            av2[2 * e + 1].x = a.z; av2[2 * e + 1].y = a.w;
        }
    }

    const float pd6 = 0.6f * aux[AUX_PD + (size_t)rel * NNODES + d];
    const float hlv = aux[AUX_HL + (size_t)td * NNODES + d] + clv;
    const float hrv = aux[AUX_HR + (size_t)td * NNODES + d] + crv;
    const float a0 = elu_f(hlv + hrv);           // att_self (pre-softmax)
    const float* psb = aux + AUX_PS + (size_t)rel * NNODES;

    const int p0  = row_start[nd];
    const int cnt = row_start[nd + 1] - p0;
    float den = 0.f;
    f32x2 acc2[8];
#pragma unroll
    for (int e = 0; e < 8; ++e) { acc2[e].x = 0.f; acc2[e].y = 0.f; }

// process two edges from raw uint4 regs
#define PROC2(X0, X1, QX, Y0, Y1, QY)                                            \
    {                                                                            \
        f32x2 fa2[8], fb2[8];                                                    \
        fa2[0] = bfp2f((X0).x); fa2[1] = bfp2f((X0).y);                          \
        fa2[2] = bfp2f((X0).z); fa2[3] = bfp2f((X0).w);                          \
        fa2[4] = bfp2f((X1).x); fa2[5] = bfp2f((X1).y);                          \
        fa2[6] = bfp2f((X1).z); fa2[7] = bfp2f((X1).w);                          \
        fb2[0] = bfp2f((Y0).x); fb2[1] = bfp2f((Y0).y);                          \
        fb2[2] = bfp2f((Y0).z); fb2[3] = bfp2f((Y0).w);                          \
        fb2[4] = bfp2f((Y1).x); fb2[5] = bfp2f((Y1).y);                          \
        fb2[6] = bfp2f((Y1).z); fb2[7] = bfp2f((Y1).w);                          \
        float Sa = 0.f, Sb = 0.f;                                                \
        _Pragma("unroll")                                                        \
        for (int e = 0; e < 8; ++e) {                                            \
            f32x2 xa = fa2[e] + fd2[e];                                          \
            f32x2 xb = fb2[e] + fd2[e];                                          \
            Sa += av2[e].x * fabsf(xa.x);                                        \
            Sa += av2[e].y * fabsf(xa.y);                                        \
            Sb += av2[e].x * fabsf(xb.x);                                        \
            Sb += av2[e].y * fabsf(xb.y);                                        \
        }                                                                        \
        Sa += __shfl_xor(Sa, 1); Sb += __shfl_xor(Sb, 1);                        \
        Sa += __shfl_xor(Sa, 2); Sb += __shfl_xor(Sb, 2);                        \
        Sa += __shfl_xor(Sa, 4); Sb += __shfl_xor(Sb, 4);                        \
        Sa += __shfl_xor(Sa, 8); Sb += __shfl_xor(Sb, 8);                        \
        float wa = __expf(fmaf(0.6f, (QX), pd6) + 0.4f * Sa);                    \
        float wb = __expf(fmaf(0.6f, (QY), pd6) + 0.4f * Sb);                    \
        den += wa + wb;                                                          \
        _Pragma("unroll")                                                        \
        for (int e = 0; e < 8; ++e) acc2[e] += wa * fa2[e] + wb * fb2[e];        \
    }

    for (int base = 0; base < cnt; base += 16) {
        int nloc = min(16, cnt - base);
        int sv = 0; float psl = 0.f;
        if (base + l < cnt) { sv = sorted_src[p0 + base + l]; psl = psb[sv]; }
        int j = 0;
        for (; j + 4 <= nloc; j += 4) {   // issue 4 edges' loads, process 2+2
            int s0 = __shfl(sv, gBase + j);
            int s1 = __shfl(sv, gBase + j + 1);
            int s2 = __shfl(sv, gBase + j + 2);
            int s3 = __shfl(sv, gBase + j + 3);
            float q0 = __shfl(psl, gBase + j);
            float q1 = __shfl(psl, gBase + j + 1);
            float q2 = __shfl(psl, gBase + j + 2);
            float q3 = __shfl(psl, gBase + j + 3);
            const unsigned short* rp0 = &ftS[(size_t)s0 * 768 + l * 16];
            const unsigned short* rp1 = &ftS[(size_t)s1 * 768 + l * 16];
            const unsigned short* rp2 = &ftS[(size_t)s2 * 768 + l * 16];
            const unsigned short* rp3 = &ftS[(size_t)s3 * 768 + l * 16];
            uint4 A0 = *reinterpret_cast<const uint4*>(rp0);
            uint4 A1 = *reinterpret_cast<const uint4*>(rp0 + 8);
            uint4 B0 = *reinterpret_cast<const uint4*>(rp1);
            uint4 B1 = *reinterpret_cast<const uint4*>(rp1 + 8);
            uint4 C0 = *reinterpret_cast<const uint4*>(rp2);
            uint4 C1 = *reinterpret_cast<const uint4*>(rp2 + 8);
            uint4 D0 = *reinterpret_cast<const uint4*>(rp3);
            uint4 D1 = *reinterpret_cast<const uint4*>(rp3 + 8);
            PROC2(A0, A1, q0, B0, B1, q1);
            PROC2(C0, C1, q2, D0, D1, q3);
        }
        for (; j + 2 <= nloc; j += 2) {
            int s0 = __shfl(sv, gBase + j);
            int s1 = __shfl(sv, gBase + j + 1);
            float q0 = __shfl(psl, gBase + j);
            float q1 = __shfl(psl, gBase + j + 1);
            const unsigned short* rp0 = &ftS[(size_t)s0 * 768 + l * 16];
            const unsigned short* rp1 = &ftS[(size_t)s1 * 768 + l * 16];
            uint4 A0 = *reinterpret_cast<const uint4*>(rp0);
            uint4 A1 = *reinterpret_cast<const uint4*>(rp0 + 8);
            uint4 B0 = *reinterpret_cast<const uint4*>(rp1);
            uint4 B1 = *reinterpret_cast<const uint4*>(rp1 + 8);
            PROC2(A0, A1, q0, B0, B1, q1);
        }
        if (j < nloc) {
            int s0 = __shfl(sv, gBase + j);
            float q0 = __shfl(psl, gBase + j);
            const unsigned short* rp0 = &ftS[(size_t)s0 * 768 + l * 16];
            uint4 A0 = *reinterpret_cast<const uint4*>(rp0);
            uint4 A1 = *reinterpret_cast<const uint4*>(rp0 + 8);
            f32x2 fa2[8];
            fa2[0] = bfp2f(A0.x); fa2[1] = bfp2f(A0.y); fa2[2] = bfp2f(A0.z); fa2[3] = bfp2f(A0.w);
            fa2[4] = bfp2f(A1.x); fa2[5] = bfp2f(A1.y); fa2[6] = bfp2f(A1.z); fa2[7] = bfp2f(A1.w);
            float Sa = 0.f;
#pragma unroll
            for (int e = 0; e < 8; ++e) {
                f32x2 xa = fa2[e] + fd2[e];
                Sa += av2[e].x * fabsf(xa.x);
                Sa += av2[e].y * fabsf(xa.y);
            }
            Sa += __shfl_xor(Sa, 1);
            Sa += __shfl_xor(Sa, 2);
            Sa += __shfl_xor(Sa, 4);
            Sa += __shfl_xor(Sa, 8);
            float wa = __expf(fmaf(0.6f, q0, pd6) + 0.4f * Sa);
            den += wa;
#pragma unroll
            for (int e = 0; e < 8; ++e) acc2[e] += wa * fa2[e];
        }
    }
#undef PROC2

    // ---- finalize rst row: v = acc/den + gbias
    float inv = den > 0.f ? 1.f / den : 1.f;
    const float* gb = gbias + rel * 256 + l * 16;
    const float* ulp = u_l + td * 256 + l * 16;
    f32x2 v2[8];
    float dotv = 0.f;
#pragma unroll
    for (int e = 0; e < 4; ++e) {
        float4 g = *reinterpret_cast<const float4*>(&gb[e * 4]);
        float4 u = *reinterpret_cast<const float4*>(&ulp[e * 4]);
        v2[2 * e].x     = acc2[2 * e].x     * inv + g.x;
        v2[2 * e].y     = acc2[2 * e].y     * inv + g.y;
        v2[2 * e + 1].x = acc2[2 * e + 1].x * inv + g.z;
        v2[2 * e + 1].y = acc2[2 * e + 1].y * inv + g.w;
        dotv += v2[2 * e].x * u.x + v2[2 * e].y * u.y
              + v2[2 * e + 1].x * u.z + v2[2 * e + 1].y * u.w;
    }
    dotv += __shfl_xor(dotv, 1);
    dotv += __shfl_xor(dotv, 2);
    dotv += __shfl_xor(dotv, 4);
    dotv += __shfl_xor(dotv, 8);
    const float ea = elu_f(dotv + clv + hrv);

    // ---- 2-way softmax combine + final elu, write output row
    float mx = fmaxf(a0, ea);
    float e0 = __expf(a0 - mx), e1 = __expf(ea - mx);
    float is = 1.f / (e0 + e1);
    float w0 = e0 * is, w1 = e1 * is;

    const unsigned short* zrow = zbuf + (size_t)d * 768 + l * 16;
    uint4 z0 = *reinterpret_cast<const uint4*>(zrow);
    uint4 z1 = *reinterpret_cast<const uint4*>(zrow + 8);
    f32x2 zf2[8];
    zf2[0] = bfp2f(z0.x); zf2[1] = bfp2f(z0.y); zf2[2] = bfp2f(z0.z); zf2[3] = bfp2f(z0.w);
    zf2[4] = bfp2f(z1.x); zf2[5] = bfp2f(z1.y); zf2[6] = bfp2f(z1.z); zf2[7] = bfp2f(z1.w);

    float* orow = out + ((size_t)(1 - rel) * NNODES + d) * 256 + l * 16;
#pragma unroll
    for (int e = 0; e < 4; ++e) {
        float4 o;
        o.x = elu_f(w0 * zf2[2 * e].x     + w1 * v2[2 * e].x);
        o.y = elu_f(w0 * zf2[2 * e].y     + w1 * v2[2 * e].y);
        o.z = elu_f(w0 * zf2[2 * e + 1].x + w1 * v2[2 * e + 1].x);
        o.w = elu_f(w0 * zf2[2 * e + 1].y + w1 * v2[2 * e + 1].y);
        *reinterpret_cast<float4*>(&orow[e * 4]) = o;
    }
}

extern "C" void kernel_launch(void* const* d_in, const int* in_sizes, int n_in,
                              void* d_out, int out_size, void* d_ws, size_t ws_size,
                              hipStream_t stream) {
    const float* hA     = (const float*)d_in[0];
    const float* hB     = (const float*)d_in[1];
    const float* Wself  = (const float*)d_in[2];
    const float* bself  = (const float*)d_in[3];
    const float* Wq     = (const float*)d_in[4];
    const float* bq     = (const float*)d_in[5];
    const float* Wk     = (const float*)d_in[6];
    const float* bk     = (const float*)d_in[7];
    const float* Wal    = (const float*)d_in[8];
    const float* bal    = (const float*)d_in[9];
    const float* War    = (const float*)d_in[10];
    const float* bar    = (const float*)d_in[11];
    const float* Wsrc   = (const float*)d_in[12];
    const float* bsrc   = (const float*)d_in[13];
    const float* Wdst   = (const float*)d_in[14];
    const float* bdst   = (const float*)d_in[15];
    const float* attn_v = (const float*)d_in[16];
    const float* gbias  = (const float*)d_in[17];
    const int* eab_src  = (const int*)d_in[18];
    const int* eab_dst  = (const int*)d_in[19];
    const int* eba_src  = (const int*)d_in[20];
    const int* eba_dst  = (const int*)d_in[21];
    float* out = (float*)d_out;
    char* ws = (char*)d_ws;

    // ---- workspace layout (256B-aligned blocks)
    const size_t SZ_BUF = (size_t)NNODES * 768 * sizeof(unsigned short);  // 76.8 MB
    const size_t SZ_H   = (size_t)NNODES * 256 * sizeof(unsigned short);  // 25.6 MB
    size_t off = 0;
    auto alloc = [&](size_t bytes) { void* p = ws + off; off = (off + bytes + 255) & ~(size_t)255; return p; };
    unsigned short* bufA = (unsigned short*)alloc(SZ_BUF);  // [z0 | ftS_ab | ftD_ba]
    unsigned short* bufB = (unsigned short*)alloc(SZ_BUF);  // [z1 | ftS_ba | ftD_ab]
    unsigned short* hAb  = (unsigned short*)alloc(SZ_H);
    unsigned short* hBb  = (unsigned short*)alloc(SZ_H);
    unsigned short* Wt   = (unsigned short*)alloc(2 * 768 * 256 * sizeof(unsigned short));
    float* biasF   = (float*)alloc(2 * 768 * sizeof(float));
    // zero-init span: aux | counts | deghist (single memset)
    float* aux     = (float*)alloc((size_t)8 * NNODES * sizeof(float));   // ps|pd|hl|hr
    int* counts    = (int*)alloc(NBINS * sizeof(int));
    int* deghist   = (int*)alloc(64 * sizeof(int));
    size_t zspan   = (char*)(deghist + 64) - (char*)aux;
    int* row_start = (int*)alloc((NBINS + 4) * sizeof(int));              // +sentinel
    int* cursor    = (int*)alloc(NBINS * sizeof(int));
    int* bsum      = (int*)alloc(512 * sizeof(int));
    int* degcur    = (int*)alloc(64 * sizeof(int));
    int* node_order= (int*)alloc(NBINS * sizeof(int));
    int* sorted_src= (int*)alloc(2 * (size_t)NEDGES * sizeof(int));
    float* u_l     = (float*)alloc(2 * 256 * sizeof(float));
    float* u_r     = (float*)alloc(2 * 256 * sizeof(float));
    float* c_l     = (float*)alloc(2 * sizeof(float));
    float* c_r     = (float*)alloc(2 * sizeof(float));

    hipMemsetAsync(aux, 0, zspan, stream);

    // ---- fused conv + hist + prep (independent work, one dispatch)
    const int HN = NNODES * 256;
    fused_prep<<<CONV_B + HIST_B + PREP_B, 256, 0, stream>>>(
        hA, hB, hAb, hBb, HN,
        eab_dst, eba_dst, counts,
        Wself, Wsrc, Wdst, bself, bsrc, bdst,
        Wq, bq, Wk, bk, Wal, bal, War, bar,
        Wt, biasF, u_l, u_r, c_l, c_r);

    // ---- scans (2 dispatches) + scatter (edges + degree-sorted nodes)
    const int sblocks = (NBINS + 1023) / 1024;   // 98
    scan1v<<<sblocks, 256, 0, stream>>>(counts, row_start, bsum, deghist, NBINS);
    scan23v<<<sblocks, 256, 0, stream>>>(counts, row_start, bsum, cursor,
                                         deghist, degcur, NBINS, sblocks);
    scatter2n<<<HIST_B + (NBINS + 255) / 256, 256, 0, stream>>>(
        eab_src, eab_dst, eba_src, eba_dst, cursor, sorted_src,
        row_start, degcur, node_order);

    // ---- fused MFMA GEMM (both types, one dispatch) + aux node-dots
    gemm_mfma<<<NWG_GEMM, 256, 0, stream>>>(hAb, hBb, Wt, biasF, attn_v, u_l, u_r,
                                            bufA, bufB, aux, NNODES);

    // ---- fully fused GAT + node attention + combine (degree-sorted)
    gat_fused<<<(2 * NNODES + 15) / 16, 256, 0, stream>>>(bufA, bufB, sorted_src, row_start,
                                                          node_order, attn_v, gbias, u_l,
                                                          c_l, c_r, aux, out);
}

// Round 12
// 267.472 us; speedup vs baseline: 2.4043x; 2.4043x over previous
//
#include <hip/hip_runtime.h>
#include <math.h>

#define NNODES 50000
#define NEDGES 262144
#define NEG_SLOPE 0.2f
#define NBINS (2 * NNODES)
#define NXP 391                    // ceil(50000/128)
#define NWG_GEMM (2 * NXP * 6)     // 4692

// fused_prep block ranges
#define CONV_B 25000               // 2*HN/4/256
#define HIST_B 2048                // 2*NEDGES/256
#define PREP_B 1538                // 2 + 2*768

typedef __attribute__((ext_vector_type(8))) short short8;   // 8 x bf16 (16B)
typedef __attribute__((ext_vector_type(4))) float f32x4;    // MFMA acc
typedef __attribute__((ext_vector_type(2))) float f32x2;
typedef __attribute__((ext_vector_type(4))) unsigned short u16x4;

// aux layout (floats): [0,2N) ps per rel (rel*N+src) ; [2N,4N) pd per rel ;
//                      [4N,6N) hl per type (t*N+node) ; [6N,8N) hr per type
#define AUX_PS 0
#define AUX_PD (2 * NNODES)
#define AUX_HL (4 * NNODES)
#define AUX_HR (6 * NNODES)

// ---------- helpers ----------
__device__ __forceinline__ float elu_f(float x) { return x > 0.f ? x : (__expf(x) - 1.f); }
__device__ __forceinline__ float bf2f(unsigned short u) {
    return __uint_as_float(((unsigned)u) << 16);
}
__device__ __forceinline__ f32x2 bfp2f(unsigned p) {   // 2 packed bf16 -> 2 f32
    f32x2 r;
    r.x = __uint_as_float(p << 16);
    r.y = __uint_as_float(p & 0xffff0000u);
    return r;
}
__device__ __forceinline__ unsigned short f2bf(float f) {
    unsigned u = __float_as_uint(f);
    unsigned r = (u + 0x7fffu + ((u >> 16) & 1u)) >> 16;   // RNE
    return (unsigned short)r;
}

// ---------- fused: f32->bf16 conv (hA,hB) + edge histogram + weight pack + uv precompute
__global__ __launch_bounds__(256) void fused_prep(
    const float* __restrict__ hA, const float* __restrict__ hB,
    unsigned short* __restrict__ hAb, unsigned short* __restrict__ hBb, int half,
    const int* __restrict__ dab, const int* __restrict__ dba, int* __restrict__ counts,
    const float* __restrict__ Wself, const float* __restrict__ Wsrc, const float* __restrict__ Wdst,
    const float* __restrict__ bself, const float* __restrict__ bsrc, const float* __restrict__ bdst,
    const float* __restrict__ Wq, const float* __restrict__ bq,
    const float* __restrict__ Wk, const float* __restrict__ bk,
    const float* __restrict__ Wal, const float* __restrict__ bal,
    const float* __restrict__ War, const float* __restrict__ bar,
    unsigned short* __restrict__ Wt, float* __restrict__ biasF,
    float* __restrict__ u_l, float* __restrict__ u_r,
    float* __restrict__ c_l, float* __restrict__ c_r)
{
    int b = blockIdx.x;
    if (b < CONV_B) {
        int i = (b * 256 + threadIdx.x) * 4;
        if (i >= 2 * half) return;
        const float* in = (i < half) ? hA : hB;
        unsigned short* out = (i < half) ? hAb : hBb;
        int k = (i < half) ? i : i - half;
        float4 v = *reinterpret_cast<const float4*>(&in[k]);
        u16x4 o;
        o[0] = f2bf(v.x); o[1] = f2bf(v.y); o[2] = f2bf(v.z); o[3] = f2bf(v.w);
        *reinterpret_cast<u16x4*>(&out[k]) = o;
        return;
    }
    if (b < CONV_B + HIST_B) {
        int e = (b - CONV_B) * 256 + threadIdx.x;
        if (e < NEDGES) atomicAdd(&counts[dab[e]], 1);
        else atomicAdd(&counts[NNODES + dba[e - NEDGES]], 1);
        return;
    }
    int pb = b - CONV_B - HIST_B;
    if (pb < 2) {
        int t = pb;
        int d = threadIdx.x;
        float sl = 0.f, sr = 0.f;
        for (int j = 0; j < 64; ++j) {
            sl += Wk[((size_t)t * 256 + d) * 64 + j] * Wal[t * 64 + j];
            sr += Wq[((size_t)t * 256 + d) * 64 + j] * War[t * 64 + j];
        }
        u_l[t * 256 + d] = sl;
        u_r[t * 256 + d] = sr;
        if (d == 0) {
            float cl = bal[t], cr = bar[t];
            for (int j = 0; j < 64; ++j) {
                cl += bk[t * 64 + j] * Wal[t * 64 + j];
                cr += bq[t * 64 + j] * War[t * 64 + j];
            }
            c_l[t] = cl; c_r[t] = cr;
        }
        return;
    }
    int r = pb - 2;                // 0..1535 = t*768 + n
    int t = r / 768;
    int n = r % 768;
    int seg = n >> 8;
    int nn = n & 255;
    const float* W; const float* bv; int ti;
    if (seg == 0)      { W = Wself; bv = bself; ti = t; }
    else if (seg == 1) { W = Wsrc;  bv = bsrc;  ti = t; }
    else               { W = Wdst;  bv = bdst;  ti = 1 - t; }
    int k = threadIdx.x;
    float val = W[(size_t)ti * 65536 + (size_t)k * 256 + nn];
    Wt[(size_t)r * 256 + k] = f2bf(val);
    if (k == 0) biasF[r] = bv[ti * 256 + nn];
}

// ---------- scan step 1 (vectorized, 1024 bins/block) + degree histogram ----------
__global__ __launch_bounds__(256) void scan1v(const int* __restrict__ counts,
                                              int* __restrict__ incl,
                                              int* __restrict__ bsum,
                                              int* __restrict__ deghist, int n) {
    __shared__ int s[256];
    __shared__ int dh[64];
    int t = threadIdx.x;
    if (t < 64) dh[t] = 0;
    int base = blockIdx.x * 1024 + t * 4;
    int4 v = make_int4(0, 0, 0, 0);
    if (base < n) v = *reinterpret_cast<const int4*>(&counts[base]);
    int l0 = v.x, l1 = l0 + v.y, l2 = l1 + v.z, l3 = l2 + v.w;
    s[t] = l3;
    __syncthreads();
    if (base < n) {    // degree histogram (LDS-local, merged to global below)
        atomicAdd(&dh[min(v.x, 63)], 1);
        atomicAdd(&dh[min(v.y, 63)], 1);
        atomicAdd(&dh[min(v.z, 63)], 1);
        atomicAdd(&dh[min(v.w, 63)], 1);
    }
#pragma unroll
    for (int off = 1; off < 256; off <<= 1) {
        int x = (t >= off) ? s[t - off] : 0;
        __syncthreads();
        s[t] += x;
        __syncthreads();
    }
    int ex = s[t] - l3;
    if (base < n)
        *reinterpret_cast<int4*>(&incl[base]) = make_int4(ex + l0, ex + l1, ex + l2, ex + l3);
    if (t == 255) bsum[blockIdx.x] = s[255];
    __syncthreads();
    if (t < 64 && dh[t]) atomicAdd(&deghist[t], dh[t]);
}

// ---------- scan steps 2+3 merged: each block locally scans bsum (nb<=128);
// writes row_start (exclusive + sentinel), cursor; block 0 computes descending deg offsets.
__global__ __launch_bounds__(256) void scan23v(const int* __restrict__ counts,
                                               int* __restrict__ incl_to_rs,
                                               const int* __restrict__ bsum,
                                               int* __restrict__ cursor,
                                               const int* __restrict__ deghist,
                                               int* __restrict__ degcur,
                                               int n, int nb) {
    __shared__ int s[128];
    int t = threadIdx.x;
    if (t < 128) s[t] = (t < nb) ? bsum[t] : 0;
    __syncthreads();
#pragma unroll
    for (int off = 1; off < 128; off <<= 1) {
        int x = 0;
        if (t < 128 && t >= off) x = s[t - off];
        __syncthreads();
        if (t < 128) s[t] += x;
        __syncthreads();
    }
    if (blockIdx.x == 0 && t == 0) {
        incl_to_rs[n] = s[nb - 1];               // sentinel = total edges
        int off = 0;                              // descending-degree exclusive offsets
        for (int b2 = 63; b2 >= 0; --b2) { degcur[b2] = off; off += deghist[b2]; }
    }
    int base = blockIdx.x * 1024 + t * 4;
    if (base >= n) return;
    int bofs = (blockIdx.x > 0) ? s[blockIdx.x - 1] : 0;
    int4 ic = *reinterpret_cast<const int4*>(&incl_to_rs[base]);
    int4 cn = *reinterpret_cast<const int4*>(&counts[base]);
    int4 st = make_int4(bofs + ic.x - cn.x, bofs + ic.y - cn.y,
                        bofs + ic.z - cn.z, bofs + ic.w - cn.w);
    *reinterpret_cast<int4*>(&incl_to_rs[base]) = st;
    *reinterpret_cast<int4*>(&cursor[base]) = st;
}

// ---------- edge scatter + degree-sorted node scatter (LDS-aggregated, G12) ----------
__global__ __launch_bounds__(256) void scatter2n(const int* __restrict__ sab,
                                                 const int* __restrict__ dab,
                                                 const int* __restrict__ sba,
                                                 const int* __restrict__ dba,
                                                 int* __restrict__ cursor,
                                                 int* __restrict__ sorted_src,
                                                 const int* __restrict__ row_start,
                                                 int* __restrict__ degcur,
                                                 int* __restrict__ node_order) {
    int b = blockIdx.x;
    if (b < HIST_B) {
        int e = b * 256 + threadIdx.x;
        if (e < NEDGES) {
            int pos = atomicAdd(&cursor[dab[e]], 1);
            sorted_src[pos] = sab[e];
        } else {
            int k = e - NEDGES;
            int pos = atomicAdd(&cursor[NNODES + dba[k]], 1);
            sorted_src[pos] = sba[k];
        }
        return;
    }
    // node scatter: per-block LDS histogram -> ONE global atomic per (block,bin)
    __shared__ int lh[64];    // local counts
    __shared__ int lb[64];    // claimed global base
    const int t = threadIdx.x;
    int idx = (b - HIST_B) * 256 + t;
    bool ok = idx < NBINS;
    int bin = 0;
    if (ok) {
        int cnt = row_start[idx + 1] - row_start[idx];
        bin = min(cnt, 63);
    }
    if (t < 64) lh[t] = 0;
    __syncthreads();
    int myofs = 0;
    if (ok) myofs = atomicAdd(&lh[bin], 1);          // LDS atomic
    __syncthreads();
    if (t < 64) {
        int c = lh[t];
        lb[t] = c ? atomicAdd(&degcur[t], c) : 0;    // <=64 global atomics/block
    }
    __syncthreads();
    if (ok) node_order[lb[bin] + myofs] = idx;
}

// ---------- fused bf16 MFMA GEMM (R7 structure, known-good ~90us) ----------
__global__ __launch_bounds__(256, 4) void gemm_mfma(
    const unsigned short* __restrict__ hAb,
    const unsigned short* __restrict__ hBb,
    const unsigned short* __restrict__ Wt,
    const float* __restrict__ biasF,
    const float* __restrict__ attn_v,
    const float* __restrict__ u_l,
    const float* __restrict__ u_r,
    unsigned short* __restrict__ bufA,
    unsigned short* __restrict__ bufB,
    float* __restrict__ aux,
    int M)
{
    __shared__ unsigned short lds[16384];   // 32 KB: 4x8KB stage bufs; reused as C tile
    const int tid = threadIdx.x;
    const int lane = tid & 63;
    const int w = tid >> 6;
    const int wm = w >> 1, wn = w & 1;

    // bijective XCD swizzle (m204)
    const int nwg = NWG_GEMM;
    const int q = nwg / 8, r = nwg % 8;
    int orig = blockIdx.x;
    int xcd = orig % 8, idx = orig / 8;
    int wgid = (xcd < r) ? (xcd * (q + 1) + idx) : (r * (q + 1) + (xcd - r) * q + idx);
    int t   = wgid / (NXP * 6);
    int rem = wgid % (NXP * 6);
    int xp  = rem / 6;
    int yc  = rem % 6;

    const int row0 = xp * 128;
    const int col0 = yc * 128;
    const unsigned short* Ain = t ? hBb : hAb;
    const unsigned short* Wtt = Wt + (size_t)t * 768 * 256;
    const float* bias = biasF + t * 768;
    unsigned short* Cout = t ? bufB : bufA;

    f32x4 acc[4][4] = {};

    const unsigned short* gA[2];
    const unsigned short* gB[2];
#pragma unroll
    for (int rr = 0; rr < 2; ++rr) {
        int qq = rr * 256 + tid;
        int row = qq >> 2;
        int c = (qq & 3) ^ ((row >> 1) & 3);
        int ga = min(row0 + row, M - 1);
        gA[rr] = Ain + (size_t)ga * 256 + c * 8;
        gB[rr] = Wtt + (size_t)(col0 + row) * 256 + c * 8;
    }

#define STAGE(buf, kt)                                                                   \
    {                                                                                    \
        unsigned short* Ad = lds + (buf) * 4096;                                         \
        unsigned short* Bd = lds + 8192 + (buf) * 4096;                                  \
        _Pragma("unroll")                                                                \
        for (int rr = 0; rr < 2; ++rr) {                                                 \
            __builtin_amdgcn_global_load_lds(                                            \
                (const __attribute__((address_space(1))) unsigned int*)(gA[rr] + (kt)),  \
                (__attribute__((address_space(3))) unsigned int*)(Ad + ((rr * 256 + w * 64) << 3)), \
                16, 0, 0);                                                               \
            __builtin_amdgcn_global_load_lds(                                            \
                (const __attribute__((address_space(1))) unsigned int*)(gB[rr] + (kt)),  \
                (__attribute__((address_space(3))) unsigned int*)(Bd + ((rr * 256 + w * 64) << 3)), \
                16, 0, 0);                                                               \
        }                                                                                \
    }

    STAGE(0, 0);        // tile 0 (4 loads/thread)
    STAGE(1, 32);       // tile 1 (8 outstanding)

#pragma unroll
    for (int it = 0; it < 8; ++it) {
        const int cur = it & 1;
        if (it < 7) { asm volatile("s_waitcnt vmcnt(4)" ::: "memory"); }
        else        { asm volatile("s_waitcnt vmcnt(0)" ::: "memory"); }
        __builtin_amdgcn_s_barrier();
        __builtin_amdgcn_sched_barrier(0);

        const unsigned short* As = lds + cur * 4096;
        const unsigned short* Bs = lds + 8192 + cur * 4096;
        short8 a[4], b[4];
#pragma unroll
        for (int i = 0; i < 4; ++i) {
            int ar = wm * 64 + i * 16 + (lane & 15);
            a[i] = *reinterpret_cast<const short8*>(
                &As[ar * 32 + (((lane >> 4) ^ ((ar >> 1) & 3)) << 3)]);
            int br = wn * 64 + i * 16 + (lane & 15);
            b[i] = *reinterpret_cast<const short8*>(
                &Bs[br * 32 + (((lane >> 4) ^ ((br >> 1) & 3)) << 3)]);
        }
#pragma unroll
        for (int i = 0; i < 4; ++i)
#pragma unroll
            for (int j = 0; j < 4; ++j)
                acc[i][j] = __builtin_amdgcn_mfma_f32_16x16x32_bf16(a[i], b[j], acc[i][j], 0, 0, 0);

        asm volatile("s_waitcnt lgkmcnt(0)" ::: "memory");
        __builtin_amdgcn_sched_barrier(0);
        __builtin_amdgcn_s_barrier();
        if (it < 6) STAGE(cur, (it + 2) * 32);
    }
#undef STAGE

    // ---- epilogue: acc (+bias) -> LDS [128][128] bf16 with per-row col-group XOR
#pragma unroll
    for (int j = 0; j < 4; ++j) {
        int colg = wn * 4 + j;
        int ci = lane & 15;
        float bv = bias[col0 + colg * 16 + ci];
#pragma unroll
        for (int i = 0; i < 4; ++i) {
            int rowb = wm * 64 + i * 16 + ((lane >> 4) << 2);
#pragma unroll
            for (int v = 0; v < 4; ++v) {
                int row = rowb + v;
                int g2 = colg ^ ((row >> 2) & 3);
                lds[row * 128 + g2 * 16 + ci] = f2bf(acc[i][j][v] + bv);
            }
        }
    }
    __syncthreads();

    const int seg = yc >> 1;                   // 0:z, 1:ftS, 2:ftD
    const float* avp1; float* axp1;
    const float* avp2 = nullptr; float* axp2 = nullptr;
    if (seg == 0) {
        avp1 = u_l + t * 256;            axp1 = aux + AUX_HL + (size_t)t * NNODES;
        avp2 = u_r + t * 256;            axp2 = aux + AUX_HR + (size_t)t * NNODES;
    } else if (seg == 1) {
        avp1 = attn_v + t * 256;         axp1 = aux + AUX_PS + (size_t)t * NNODES;
    } else {
        avp1 = attn_v + (1 - t) * 256;   axp1 = aux + AUX_PD + (size_t)(1 - t) * NNODES;
    }

#pragma unroll
    for (int p = 0; p < 8; ++p) {
        int idx = p * 256 + tid;
        int row = idx >> 4;
        int ch = idx & 15;
        int g2 = (ch >> 1) ^ ((row >> 2) & 3);
        int grow = row0 + row;
        bool ok = grow < M;
        short8 val = *reinterpret_cast<const short8*>(&lds[row * 128 + g2 * 16 + ((ch & 1) << 3)]);
        if (ok)
            *reinterpret_cast<short8*>(&Cout[(size_t)grow * 768 + col0 + ch * 8]) = val;
        int colb = (yc & 1) * 128 + ch * 8;
        float4 w0v = *reinterpret_cast<const float4*>(&avp1[colb]);
        float4 w1v = *reinterpret_cast<const float4*>(&avp1[colb + 4]);
        float p1 = w0v.x * bf2f((unsigned short)val[0]) + w0v.y * bf2f((unsigned short)val[1])
                 + w0v.z * bf2f((unsigned short)val[2]) + w0v.w * bf2f((unsigned short)val[3])
                 + w1v.x * bf2f((unsigned short)val[4]) + w1v.y * bf2f((unsigned short)val[5])
                 + w1v.z * bf2f((unsigned short)val[6]) + w1v.w * bf2f((unsigned short)val[7]);
        p1 += __shfl_xor(p1, 1);
        p1 += __shfl_xor(p1, 2);
        p1 += __shfl_xor(p1, 4);
        p1 += __shfl_xor(p1, 8);
        if ((tid & 15) == 0 && ok) atomicAdd(&axp1[grow], p1);
        if (avp2) {
            float4 y0 = *reinterpret_cast<const float4*>(&avp2[colb]);
            float4 y1 = *reinterpret_cast<const float4*>(&avp2[colb + 4]);
            float p2 = y0.x * bf2f((unsigned short)val[0]) + y0.y * bf2f((unsigned short)val[1])
                     + y0.z * bf2f((unsigned short)val[2]) + y0.w * bf2f((unsigned short)val[3])
                     + y1.x * bf2f((unsigned short)val[4]) + y1.y * bf2f((unsigned short)val[5])
                     + y1.z * bf2f((unsigned short)val[6]) + y1.w * bf2f((unsigned short)val[7]);
            p2 += __shfl_xor(p2, 1);
            p2 += __shfl_xor(p2, 2);
            p2 += __shfl_xor(p2, 4);
            p2 += __shfl_xor(p2, 8);
            if ((tid & 15) == 0 && ok) atomicAdd(&axp2[grow], p2);
        }
    }
}

// ---------- fully fused per-dst GATv2 + node attention + combine
// 16 lanes/dst, 4 dsts/wave, DEGREE-SORTED node order (equal cnt within a wave
// -> no divergence waste). lrelu factorization; batch-4 loads / process-2.
__global__ __launch_bounds__(256) void gat_fused(
    const unsigned short* __restrict__ bufA, const unsigned short* __restrict__ bufB,
    const int* __restrict__ sorted_src, const int* __restrict__ row_start,
    const int* __restrict__ node_order,
    const float* __restrict__ attn_v, const float* __restrict__ gbias,
    const float* __restrict__ u_l,
    const float* __restrict__ c_l, const float* __restrict__ c_r,
    const float* __restrict__ aux,
    float* __restrict__ out)
{
    const int tid = threadIdx.x;
    const int l = tid & 15;            // lane in 16-group
    const int gBase = tid & 48;        // group base lane within wave
    const int nd0 = blockIdx.x * 16 + (tid >> 4);
    if (nd0 >= 2 * NNODES) return;
    const int nd = node_order[nd0];    // degree-sorted
    const int rel = nd >= NNODES;      // 0: ab (dst type B), 1: ba (dst type A)
    const int d = nd - rel * NNODES;
    const int td = rel ? 0 : 1;        // dst node type

    const unsigned short* zbuf = td ? bufB : bufA;
    const unsigned short* ftS = (rel ? bufB : bufA) + 256;
    const unsigned short* ftD = zbuf + 512;
    const float clv = c_l[td], crv = c_r[td];

    // per-lane dims [l*16, l*16+16) as f32x2 pairs
    f32x2 fd2[8], av2[8];
    {
        const unsigned short* fdp = &ftD[(size_t)d * 768 + l * 16];
        uint4 d0 = *reinterpret_cast<const uint4*>(fdp);
        uint4 d1 = *reinterpret_cast<const uint4*>(fdp + 8);
        fd2[0] = bfp2f(d0.x); fd2[1] = bfp2f(d0.y); fd2[2] = bfp2f(d0.z); fd2[3] = bfp2f(d0.w);
        fd2[4] = bfp2f(d1.x); fd2[5] = bfp2f(d1.y); fd2[6] = bfp2f(d1.z); fd2[7] = bfp2f(d1.w);
        const float* avp = attn_v + rel * 256 + l * 16;
#pragma unroll
        for (int e = 0; e < 4; ++e) {
            float4 a = *reinterpret_cast<const float4*>(&avp[e * 4]);
            av2[2 * e].x = a.x; av2[2 * e].y = a.y;
            av2[2 * e + 1].x = a.z; av2[2 * e + 1].y = a.w;
        }
    }

    const float pd6 = 0.6f * aux[AUX_PD + (size_t)rel * NNODES + d];
    const float hlv = aux[AUX_HL + (size_t)td * NNODES + d] + clv;
    const float hrv = aux[AUX_HR + (size_t)td * NNODES + d] + crv;
    const float a0 = elu_f(hlv + hrv);           // att_self (pre-softmax)
    const float* psb = aux + AUX_PS + (size_t)rel * NNODES;

    const int p0  = row_start[nd];
    const int cnt = row_start[nd + 1] - p0;
    float den = 0.f;
    f32x2 acc2[8];
#pragma unroll
    for (int e = 0; e < 8; ++e) { acc2[e].x = 0.f; acc2[e].y = 0.f; }

// process two edges from raw uint4 regs
#define PROC2(X0, X1, QX, Y0, Y1, QY)                                            \
    {                                                                            \
        f32x2 fa2[8], fb2[8];                                                    \
        fa2[0] = bfp2f((X0).x); fa2[1] = bfp2f((X0).y);                          \
        fa2[2] = bfp2f((X0).z); fa2[3] = bfp2f((X0).w);                          \
        fa2[4] = bfp2f((X1).x); fa2[5] = bfp2f((X1).y);                          \
        fa2[6] = bfp2f((X1).z); fa2[7] = bfp2f((X1).w);                          \
        fb2[0] = bfp2f((Y0).x); fb2[1] = bfp2f((Y0).y);                          \
        fb2[2] = bfp2f((Y0).z); fb2[3] = bfp2f((Y0).w);                          \
        fb2[4] = bfp2f((Y1).x); fb2[5] = bfp2f((Y1).y);                          \
        fb2[6] = bfp2f((Y1).z); fb2[7] = bfp2f((Y1).w);                          \
        float Sa = 0.f, Sb = 0.f;                                                \
        _Pragma("unroll")                                                        \
        for (int e = 0; e < 8; ++e) {                                            \
            f32x2 xa = fa2[e] + fd2[e];                                          \
            f32x2 xb = fb2[e] + fd2[e];                                          \
            Sa += av2[e].x * fabsf(xa.x);                                        \
            Sa += av2[e].y * fabsf(xa.y);                                        \
            Sb += av2[e].x * fabsf(xb.x);                                        \
            Sb += av2[e].y * fabsf(xb.y);                                        \
        }                                                                        \
        Sa += __shfl_xor(Sa, 1); Sb += __shfl_xor(Sb, 1);                        \
        Sa += __shfl_xor(Sa, 2); Sb += __shfl_xor(Sb, 2);                        \
        Sa += __shfl_xor(Sa, 4); Sb += __shfl_xor(Sb, 4);                        \
        Sa += __shfl_xor(Sa, 8); Sb += __shfl_xor(Sb, 8);                        \
        float wa = __expf(fmaf(0.6f, (QX), pd6) + 0.4f * Sa);                    \
        float wb = __expf(fmaf(0.6f, (QY), pd6) + 0.4f * Sb);                    \
        den += wa + wb;                                                          \
        _Pragma("unroll")                                                        \
        for (int e = 0; e < 8; ++e) acc2[e] += wa * fa2[e] + wb * fb2[e];        \
    }

    for (int base = 0; base < cnt; base += 16) {
        int nloc = min(16, cnt - base);
        int sv = 0; float psl = 0.f;
        if (base + l < cnt) { sv = sorted_src[p0 + base + l]; psl = psb[sv]; }
        int j = 0;
        for (; j + 4 <= nloc; j += 4) {   // issue 4 edges' loads, process 2+2
            int s0 = __shfl(sv, gBase + j);
            int s1 = __shfl(sv, gBase + j + 1);
            int s2 = __shfl(sv, gBase + j + 2);
            int s3 = __shfl(sv, gBase + j + 3);
            float q0 = __shfl(psl, gBase + j);
            float q1 = __shfl(psl, gBase + j + 1);
            float q2 = __shfl(psl, gBase + j + 2);
            float q3 = __shfl(psl, gBase + j + 3);
            const unsigned short* rp0 = &ftS[(size_t)s0 * 768 + l * 16];
            const unsigned short* rp1 = &ftS[(size_t)s1 * 768 + l * 16];
            const unsigned short* rp2 = &ftS[(size_t)s2 * 768 + l * 16];
            const unsigned short* rp3 = &ftS[(size_t)s3 * 768 + l * 16];
            uint4 A0 = *reinterpret_cast<const uint4*>(rp0);
            uint4 A1 = *reinterpret_cast<const uint4*>(rp0 + 8);
            uint4 B0 = *reinterpret_cast<const uint4*>(rp1);
            uint4 B1 = *reinterpret_cast<const uint4*>(rp1 + 8);
            uint4 C0 = *reinterpret_cast<const uint4*>(rp2);
            uint4 C1 = *reinterpret_cast<const uint4*>(rp2 + 8);
            uint4 D0 = *reinterpret_cast<const uint4*>(rp3);
            uint4 D1 = *reinterpret_cast<const uint4*>(rp3 + 8);
            PROC2(A0, A1, q0, B0, B1, q1);
            PROC2(C0, C1, q2, D0, D1, q3);
        }
        for (; j + 2 <= nloc; j += 2) {
            int s0 = __shfl(sv, gBase + j);
            int s1 = __shfl(sv, gBase + j + 1);
            float q0 = __shfl(psl, gBase + j);
            float q1 = __shfl(psl, gBase + j + 1);
            const unsigned short* rp0 = &ftS[(size_t)s0 * 768 + l * 16];
            const unsigned short* rp1 = &ftS[(size_t)s1 * 768 + l * 16];
            uint4 A0 = *reinterpret_cast<const uint4*>(rp0);
            uint4 A1 = *reinterpret_cast<const uint4*>(rp0 + 8);
            uint4 B0 = *reinterpret_cast<const uint4*>(rp1);
            uint4 B1 = *reinterpret_cast<const uint4*>(rp1 + 8);
            PROC2(A0, A1, q0, B0, B1, q1);
        }
        if (j < nloc) {
            int s0 = __shfl(sv, gBase + j);
            float q0 = __shfl(psl, gBase + j);
            const unsigned short* rp0 = &ftS[(size_t)s0 * 768 + l * 16];
            uint4 A0 = *reinterpret_cast<const uint4*>(rp0);
            uint4 A1 = *reinterpret_cast<const uint4*>(rp0 + 8);
            f32x2 fa2[8];
            fa2[0] = bfp2f(A0.x); fa2[1] = bfp2f(A0.y); fa2[2] = bfp2f(A0.z); fa2[3] = bfp2f(A0.w);
            fa2[4] = bfp2f(A1.x); fa2[5] = bfp2f(A1.y); fa2[6] = bfp2f(A1.z); fa2[7] = bfp2f(A1.w);
            float Sa = 0.f;
#pragma unroll
            for (int e = 0; e < 8; ++e) {
                f32x2 xa = fa2[e] + fd2[e];
                Sa += av2[e].x * fabsf(xa.x);
                Sa += av2[e].y * fabsf(xa.y);
            }
            Sa += __shfl_xor(Sa, 1);
            Sa += __shfl_xor(Sa, 2);
            Sa += __shfl_xor(Sa, 4);
            Sa += __shfl_xor(Sa, 8);
            float wa = __expf(fmaf(0.6f, q0, pd6) + 0.4f * Sa);
            den += wa;
#pragma unroll
            for (int e = 0; e < 8; ++e) acc2[e] += wa * fa2[e];
        }
    }
#undef PROC2

    // ---- finalize rst row: v = acc/den + gbias
    float inv = den > 0.f ? 1.f / den : 1.f;
    const float* gb = gbias + rel * 256 + l * 16;
    const float* ulp = u_l + td * 256 + l * 16;
    f32x2 v2[8];
    float dotv = 0.f;
#pragma unroll
    for (int e = 0; e < 4; ++e) {
        float4 g = *reinterpret_cast<const float4*>(&gb[e * 4]);
        float4 u = *reinterpret_cast<const float4*>(&ulp[e * 4]);
        v2[2 * e].x     = acc2[2 * e].x     * inv + g.x;
        v2[2 * e].y     = acc2[2 * e].y     * inv + g.y;
        v2[2 * e + 1].x = acc2[2 * e + 1].x * inv + g.z;
        v2[2 * e + 1].y = acc2[2 * e + 1].y * inv + g.w;
        dotv += v2[2 * e].x * u.x + v2[2 * e].y * u.y
              + v2[2 * e + 1].x * u.z + v2[2 * e + 1].y * u.w;
    }
    dotv += __shfl_xor(dotv, 1);
    dotv += __shfl_xor(dotv, 2);
    dotv += __shfl_xor(dotv, 4);
    dotv += __shfl_xor(dotv, 8);
    const float ea = elu_f(dotv + clv + hrv);

    // ---- 2-way softmax combine + final elu, write output row
    float mx = fmaxf(a0, ea);
    float e0 = __expf(a0 - mx), e1 = __expf(ea - mx);
    float is = 1.f / (e0 + e1);
    float w0 = e0 * is, w1 = e1 * is;

    const unsigned short* zrow = zbuf + (size_t)d * 768 + l * 16;
    uint4 z0 = *reinterpret_cast<const uint4*>(zrow);
    uint4 z1 = *reinterpret_cast<const uint4*>(zrow + 8);
    f32x2 zf2[8];
    zf2[0] = bfp2f(z0.x); zf2[1] = bfp2f(z0.y); zf2[2] = bfp2f(z0.z); zf2[3] = bfp2f(z0.w);
    zf2[4] = bfp2f(z1.x); zf2[5] = bfp2f(z1.y); zf2[6] = bfp2f(z1.z); zf2[7] = bfp2f(z1.w);

    float* orow = out + ((size_t)(1 - rel) * NNODES + d) * 256 + l * 16;
#pragma unroll
    for (int e = 0; e < 4; ++e) {
        float4 o;
        o.x = elu_f(w0 * zf2[2 * e].x     + w1 * v2[2 * e].x);
        o.y = elu_f(w0 * zf2[2 * e].y     + w1 * v2[2 * e].y);
        o.z = elu_f(w0 * zf2[2 * e + 1].x + w1 * v2[2 * e + 1].x);
        o.w = elu_f(w0 * zf2[2 * e + 1].y + w1 * v2[2 * e + 1].y);
        *reinterpret_cast<float4*>(&orow[e * 4]) = o;
    }
}

extern "C" void kernel_launch(void* const* d_in, const int* in_sizes, int n_in,
                              void* d_out, int out_size, void* d_ws, size_t ws_size,
                              hipStream_t stream) {
    const float* hA     = (const float*)d_in[0];
    const float* hB     = (const float*)d_in[1];
    const float* Wself  = (const float*)d_in[2];
    const float* bself  = (const float*)d_in[3];
    const float* Wq     = (const float*)d_in[4];
    const float* bq     = (const float*)d_in[5];
    const float* Wk     = (const float*)d_in[6];
    const float* bk     = (const float*)d_in[7];
    const float* Wal    = (const float*)d_in[8];
    const float* bal    = (const float*)d_in[9];
    const float* War    = (const float*)d_in[10];
    const float* bar    = (const float*)d_in[11];
    const float* Wsrc   = (const float*)d_in[12];
    const float* bsrc   = (const float*)d_in[13];
    const float* Wdst   = (const float*)d_in[14];
    const float* bdst   = (const float*)d_in[15];
    const float* attn_v = (const float*)d_in[16];
    const float* gbias  = (const float*)d_in[17];
    const int* eab_src  = (const int*)d_in[18];
    const int* eab_dst  = (const int*)d_in[19];
    const int* eba_src  = (const int*)d_in[20];
    const int* eba_dst  = (const int*)d_in[21];
    float* out = (float*)d_out;
    char* ws = (char*)d_ws;

    // ---- workspace layout (256B-aligned blocks)
    const size_t SZ_BUF = (size_t)NNODES * 768 * sizeof(unsigned short);  // 76.8 MB
    const size_t SZ_H   = (size_t)NNODES * 256 * sizeof(unsigned short);  // 25.6 MB
    size_t off = 0;
    auto alloc = [&](size_t bytes) { void* p = ws + off; off = (off + bytes + 255) & ~(size_t)255; return p; };
    unsigned short* bufA = (unsigned short*)alloc(SZ_BUF);  // [z0 | ftS_ab | ftD_ba]
    unsigned short* bufB = (unsigned short*)alloc(SZ_BUF);  // [z1 | ftS_ba | ftD_ab]
    unsigned short* hAb  = (unsigned short*)alloc(SZ_H);
    unsigned short* hBb  = (unsigned short*)alloc(SZ_H);
    unsigned short* Wt   = (unsigned short*)alloc(2 * 768 * 256 * sizeof(unsigned short));
    float* biasF   = (float*)alloc(2 * 768 * sizeof(float));
    // zero-init span: aux | counts | deghist (single memset)
    float* aux     = (float*)alloc((size_t)8 * NNODES * sizeof(float));   // ps|pd|hl|hr
    int* counts    = (int*)alloc(NBINS * sizeof(int));
    int* deghist   = (int*)alloc(64 * sizeof(int));
    size_t zspan   = (char*)(deghist + 64) - (char*)aux;
    int* row_start = (int*)alloc((NBINS + 4) * sizeof(int));              // +sentinel
    int* cursor    = (int*)alloc(NBINS * sizeof(int));
    int* bsum      = (int*)alloc(512 * sizeof(int));
    int* degcur    = (int*)alloc(64 * sizeof(int));
    int* node_order= (int*)alloc(NBINS * sizeof(int));
    int* sorted_src= (int*)alloc(2 * (size_t)NEDGES * sizeof(int));
    float* u_l     = (float*)alloc(2 * 256 * sizeof(float));
    float* u_r     = (float*)alloc(2 * 256 * sizeof(float));
    float* c_l     = (float*)alloc(2 * sizeof(float));
    float* c_r     = (float*)alloc(2 * sizeof(float));

    hipMemsetAsync(aux, 0, zspan, stream);

    // ---- fused conv + hist + prep (independent work, one dispatch)
    const int HN = NNODES * 256;
    fused_prep<<<CONV_B + HIST_B + PREP_B, 256, 0, stream>>>(
        hA, hB, hAb, hBb, HN,
        eab_dst, eba_dst, counts,
        Wself, Wsrc, Wdst, bself, bsrc, bdst,
        Wq, bq, Wk, bk, Wal, bal, War, bar,
        Wt, biasF, u_l, u_r, c_l, c_r);

    // ---- scans (2 dispatches) + scatter (edges + degree-sorted nodes)
    const int sblocks = (NBINS + 1023) / 1024;   // 98
    scan1v<<<sblocks, 256, 0, stream>>>(counts, row_start, bsum, deghist, NBINS);
    scan23v<<<sblocks, 256, 0, stream>>>(counts, row_start, bsum, cursor,
                                         deghist, degcur, NBINS, sblocks);
    scatter2n<<<HIST_B + (NBINS + 255) / 256, 256, 0, stream>>>(
        eab_src, eab_dst, eba_src, eba_dst, cursor, sorted_src,
        row_start, degcur, node_order);

    // ---- fused MFMA GEMM (both types, one dispatch) + aux node-dots
    gemm_mfma<<<NWG_GEMM, 256, 0, stream>>>(hAb, hBb, Wt, biasF, attn_v, u_l, u_r,
                                            bufA, bufB, aux, NNODES);

    // ---- fully fused GAT + node attention + combine (degree-sorted)
    gat_fused<<<(2 * NNODES + 15) / 16, 256, 0, stream>>>(bufA, bufB, sorted_src, row_start,
                                                          node_order, attn_v, gbias, u_l,
                                                          c_l, c_r, aux, out);
}